// Round 13
// baseline (466.784 us; speedup 1.0000x reference)
//
#include <hip/hip_runtime.h>

// Scaled-dot-product attention, bs=4, h=16, S=2048, D=64, f32 in/out.
// Outputs O [64,2048,64] and P=attn_weights [64,2048,2048] (f32, 1.07 GB write).
// Confirmed levers: full-128B-line stores (R7 +13%); nt stores bypassing L2
// write-allocate (R10 +25%).
// R13 model: vmcnt retires IN ORDER per wave; nt store acks come from the
// memory controller (slow). Every iteration's K/V loads sit behind the prior
// iteration's nt stores -> iter_time ~ store-ack latency (~3.7us contended).
// R5/R6 never tested this (VGPR=48 proves compiler sank the prefetch).
// Fix: producer/consumer wave specialization. 4 producer waves (loads+MFMA,
// zero stores) hand P tiles through double-buffered LDS to 1 storer wave
// (zero loads, fire-and-forget nt stores, never waits on acks).

#define S_LEN 2048
#define DH 64
#define NHEADS 64  // bs*h

typedef short short8 __attribute__((ext_vector_type(8)));   // 8 x bf16
typedef float f32x4 __attribute__((ext_vector_type(4)));
typedef float f32x16 __attribute__((ext_vector_type(16)));
typedef unsigned short u16;

__device__ __forceinline__ u16 f2bf(float f) {
  union { float f; unsigned u; } x;
  x.f = f;
  unsigned r = x.u + 0x7fffu + ((x.u >> 16) & 1u);  // RNE
  return (u16)(r >> 16);
}

__device__ __forceinline__ unsigned pkbf(float a, float b) {
  return (unsigned)f2bf(a) | ((unsigned)f2bf(b) << 16);  // a -> low, b -> high
}

// v_permlane32_swap_b32: new a[32+i]=old b[i]; new b[i]=old a[32+i]
__device__ __forceinline__ void plswap(unsigned& a, unsigned& b) {
  asm("v_permlane32_swap_b32 %0, %1" : "+v"(a), "+v"(b));
}

// ---- pre-pass: Q * scale -> bf16, same layout ----
__global__ __launch_bounds__(256) void cvt_scale_k(const float* __restrict__ in,
                                                   u16* __restrict__ out,
                                                   float scale, int n4) {
  int i = blockIdx.x * 256 + threadIdx.x;
  if (i >= n4) return;
  float4 v = ((const float4*)in)[i];
  union { u16 s[4]; unsigned long long ll; } o;
  o.s[0] = f2bf(v.x * scale); o.s[1] = f2bf(v.y * scale);
  o.s[2] = f2bf(v.z * scale); o.s[3] = f2bf(v.w * scale);
  ((unsigned long long*)out)[i] = o.ll;
}

// ---- pre-pass: per-head transpose [R][C] f32 -> [C][R] bf16 ----
__global__ __launch_bounds__(256) void transpose_cvt_k(const float* __restrict__ in,
                                                       u16* __restrict__ out,
                                                       int R, int C) {
  __shared__ float tile[64][65];
  const int tilesC = C >> 6;
  const int tilesPerHead = (R >> 6) * tilesC;
  int hb = blockIdx.x;
  int head = hb / tilesPerHead;
  int t = hb - head * tilesPerHead;
  int tr = t / tilesC, tc = t - tr * tilesC;
  const float* ip = in + (size_t)head * R * C + (size_t)tr * 64 * C + (size_t)tc * 64;
  u16* op = out + (size_t)head * R * C + (size_t)tc * 64 * R + (size_t)tr * 64;
  int c = threadIdx.x & 63, r0 = threadIdx.x >> 6;
#pragma unroll
  for (int k = 0; k < 16; ++k) {
    int r = (k << 2) + r0;
    tile[r][c] = ip[(size_t)r * C + c];
  }
  __syncthreads();
#pragma unroll
  for (int k = 0; k < 16; ++k) {
    int orow = (k << 2) + r0;
    op[(size_t)orow * R + c] = f2bf(tile[c][orow]);
  }
}

// ---- fused attention: 4 producer waves + 1 storer wave per block ----
// Layouts (bf16): Qb [h][s][d] (pre-scaled), Kn [h][s][d], Vt [h][d][s].
// Block = 128 q-rows; producer wv (0..3) owns rows q0 = rblk*128 + wv*32.
// mfma_f32_32x32x16_bf16:  A row=lane&31, k=(lane>>5)*8+i (8 contig)
//                          B col=lane&31, k=(lane>>5)*8+i
//                          D col=lane&31, row=(r&3)+8*(r>>2)+4*(lane>>5)
// Per j-tile: producers {compute S,p; barA; ds_write buf[t&1][wv]; barB; pack+PV}
//             storer    {barA; barB; ds_read buf[t&1] -> 16 nt full-line stores}
// Storer's vmcnt holds ONLY stores (never waited on); producers' holds only loads.
__global__ __launch_bounds__(320, 5) void attn_k(const u16* __restrict__ Qb,
                                                 const u16* __restrict__ Kn,
                                                 const u16* __restrict__ Vt,
                                                 float* __restrict__ Og,
                                                 float* __restrict__ Pg) {
  __shared__ float buf[2][4][32 * 32];  // double-buffered transposed P tiles
  int bid = blockIdx.x;
  // bijective XCD swizzle: 1024 blocks, XCD x gets heads 8x..8x+7 (K+V = 4MB = L2)
  int work = ((bid & 7) << 7) | (bid >> 3);
  int head = work >> 4;
  int rblk = work & 15;
  int lane = threadIdx.x & 63;
  int wv = threadIdx.x >> 6;   // 0..3 producers, 4 storer
  int rq = lane >> 3;          // 0..7: row-within-group for line stores
  int rc = lane & 7;           // 0..7: 16B chunk within the 128B line

  if (wv == 4) {
    // ---- storer wave: no loads ever; fire-and-forget nt stores ----
    float* pgb = Pg + ((size_t)head * S_LEN + (size_t)rblk * 128) * S_LEN;
    for (int t = 0; t < 64; ++t) {
      __syncthreads();  // bar_A (producers about to write buf[t&1])
      __syncthreads();  // bar_B (buf[t&1] ready)
      int j0 = t << 5;
      const float* tb = &buf[t & 1][0][0];
#pragma unroll
      for (int w = 0; w < 4; ++w) {
#pragma unroll
        for (int g = 0; g < 4; ++g) {
          int qi = 8 * g + rq;
          int phys = rc ^ (qi & 7);
          f32x4 v = *(const f32x4*)&tb[(w * 1024) + qi * 32 + phys * 4];
          __builtin_nontemporal_store(
              v, (f32x4*)(pgb + (size_t)(w * 32 + qi) * S_LEN + j0 + rc * 4));
        }
      }
    }
    return;
  }

  // ---- producer waves ----
  int q = lane & 31;
  int hi = lane >> 5;
  int q0 = (rblk << 7) + (wv << 5);

  // Q B-fragments, resident
  const u16* qp = Qb + (size_t)(head * S_LEN + q0 + q) * DH + hi * 8;
  short8 qf0 = *(const short8*)(qp);
  short8 qf1 = *(const short8*)(qp + 16);
  short8 qf2 = *(const short8*)(qp + 32);
  short8 qf3 = *(const short8*)(qp + 48);

  const u16* kp = Kn + (size_t)head * S_LEN * DH + (size_t)q * DH + hi * 8;
  const u16* vp = Vt + (size_t)head * DH * S_LEN + (size_t)q * S_LEN + hi * 8;

  // ---- pass 1: l[q] = sum_j exp(s)  (no barriers, no stores) ----
  float ls0 = 0.f, ls1 = 0.f, ls2 = 0.f, ls3 = 0.f;
  for (int j0 = 0; j0 < S_LEN; j0 += 32) {
    const u16* kb = kp + (size_t)j0 * DH;
    short8 k0 = *(const short8*)(kb);
    short8 k1 = *(const short8*)(kb + 16);
    short8 k2 = *(const short8*)(kb + 32);
    short8 k3 = *(const short8*)(kb + 48);
    f32x16 s = {};
    s = __builtin_amdgcn_mfma_f32_32x32x16_bf16(k0, qf0, s, 0, 0, 0);
    s = __builtin_amdgcn_mfma_f32_32x32x16_bf16(k1, qf1, s, 0, 0, 0);
    s = __builtin_amdgcn_mfma_f32_32x32x16_bf16(k2, qf2, s, 0, 0, 0);
    s = __builtin_amdgcn_mfma_f32_32x32x16_bf16(k3, qf3, s, 0, 0, 0);
#pragma unroll
    for (int r = 0; r < 16; r += 4) {
      ls0 += __expf(s[r]);
      ls1 += __expf(s[r + 1]);
      ls2 += __expf(s[r + 2]);
      ls3 += __expf(s[r + 3]);
    }
  }
  float ls = (ls0 + ls1) + (ls2 + ls3);
  ls += __shfl_xor(ls, 32);  // combine hi/lo halves (disjoint j subsets)
  float rl = 1.f / ls;

  // ---- pass 2: compute + LDS handoff (zero global stores in this wave) ----
  f32x16 oa = {}, ob = {};

  for (int t = 0; t < 64; ++t) {
    int j0 = t << 5;
    const u16* kb = kp + (size_t)j0 * DH;
    short8 k0 = *(const short8*)(kb);
    short8 k1 = *(const short8*)(kb + 16);
    short8 k2 = *(const short8*)(kb + 32);
    short8 k3 = *(const short8*)(kb + 48);
    const u16* vj = vp + j0;
    short8 v0 = *(const short8*)(vj);                     // jstep0, d 0..31
    short8 v1 = *(const short8*)(vj + 16);                // jstep1, d 0..31
    short8 v2 = *(const short8*)(vj + 32 * S_LEN);        // jstep0, d 32..63
    short8 v3 = *(const short8*)(vj + 32 * S_LEN + 16);   // jstep1, d 32..63

    f32x16 s = {};
    s = __builtin_amdgcn_mfma_f32_32x32x16_bf16(k0, qf0, s, 0, 0, 0);
    s = __builtin_amdgcn_mfma_f32_32x32x16_bf16(k1, qf1, s, 0, 0, 0);
    s = __builtin_amdgcn_mfma_f32_32x32x16_bf16(k2, qf2, s, 0, 0, 0);
    s = __builtin_amdgcn_mfma_f32_32x32x16_bf16(k3, qf3, s, 0, 0, 0);

    float p[16];
#pragma unroll
    for (int r = 0; r < 16; ++r) p[r] = __expf(s[r]) * rl;

    __syncthreads();  // bar_A: storer finished reading this buffer (t-2)

    // LDS transpose write: lane holds column q, regs 4g..4g+3 = j-chunk 2g+hi.
    // chunk-XOR swizzle keeps the column-write ~4-way instead of 32-way.
    float* tw = &buf[t & 1][wv][0];
#pragma unroll
    for (int g = 0; g < 4; ++g) {
      int phys = (2 * g + hi) ^ (q & 7);
      f32x4 w = {p[4 * g], p[4 * g + 1], p[4 * g + 2], p[4 * g + 3]};
      *(f32x4*)&tw[q * 32 + phys * 4] = w;
    }

    __syncthreads();  // bar_B: buf[t&1] ready for the storer

    // T12 redistribute from regs: D-layout -> A-frag (k = hi*8+i contiguous j)
    unsigned A0 = pkbf(p[0], p[1]),   A1 = pkbf(p[2], p[3]);
    unsigned B0 = pkbf(p[4], p[5]),   B1 = pkbf(p[6], p[7]);
    plswap(A0, B0);
    plswap(A1, B1);
    unsigned C0 = pkbf(p[8], p[9]),   C1 = pkbf(p[10], p[11]);
    unsigned D0 = pkbf(p[12], p[13]), D1 = pkbf(p[14], p[15]);
    plswap(C0, D0);
    plswap(C1, D1);
    union { unsigned w[4]; short8 v; } pa0u = {{A0, A1, B0, B1}};
    union { unsigned w[4]; short8 v; } pa1u = {{C0, C1, D0, D1}};

    oa = __builtin_amdgcn_mfma_f32_32x32x16_bf16(pa0u.v, v0, oa, 0, 0, 0);
    oa = __builtin_amdgcn_mfma_f32_32x32x16_bf16(pa1u.v, v1, oa, 0, 0, 0);
    ob = __builtin_amdgcn_mfma_f32_32x32x16_bf16(pa0u.v, v2, ob, 0, 0, 0);
    ob = __builtin_amdgcn_mfma_f32_32x32x16_bf16(pa1u.v, v3, ob, 0, 0, 0);
  }

  // ---- O epilogue: buf[0][wv] is free (last drained at t=62); wave-private ----
  float* te = &buf[0][wv][0];
  float* ogb = Og + (size_t)(head * S_LEN + q0) * DH;
#pragma unroll
  for (int r = 0; r < 16; ++r) {
    int qi = (r & 3) + 8 * (r >> 2) + 4 * hi;
    te[qi * 32 + q] = oa[r];   // bank = q -> conflict-free
  }
#pragma unroll
  for (int g = 0; g < 4; ++g) {
    int qi = 8 * g + rq;
    f32x4 v = *(const f32x4*)&te[qi * 32 + rc * 4];
    __builtin_nontemporal_store(v, (f32x4*)(ogb + (size_t)qi * DH + rc * 4));
  }
#pragma unroll
  for (int r = 0; r < 16; ++r) {
    int qi = (r & 3) + 8 * (r >> 2) + 4 * hi;
    te[qi * 32 + q] = ob[r];
  }
#pragma unroll
  for (int g = 0; g < 4; ++g) {
    int qi = 8 * g + rq;
    f32x4 v = *(const f32x4*)&te[qi * 32 + rc * 4];
    __builtin_nontemporal_store(v, (f32x4*)(ogb + (size_t)qi * DH + 32 + rc * 4));
  }
}

extern "C" void kernel_launch(void* const* d_in, const int* in_sizes, int n_in,
                              void* d_out, int out_size, void* d_ws, size_t ws_size,
                              hipStream_t stream) {
  const float* q = (const float*)d_in[0];
  const float* k = (const float*)d_in[1];  // [b,h,d,s]
  const float* v = (const float*)d_in[2];  // [b,h,s,d]
  float* Og = (float*)d_out;
  float* Pg = Og + (size_t)NHEADS * S_LEN * DH;

  const size_t elems = (size_t)NHEADS * S_LEN * DH;  // 8,388,608
  u16* Qb = (u16*)d_ws;           // bf16 [h][s][d], pre-scaled
  u16* Kn = Qb + elems;           // bf16 [h][s][d]
  u16* Vt = Kn + elems;           // bf16 [h][d][s]

  int n4 = (int)(elems / 4);
  cvt_scale_k<<<n4 / 256, 256, 0, stream>>>(q, Qb, 0.125f, n4);
  transpose_cvt_k<<<NHEADS * (S_LEN / 64), 256, 0, stream>>>(k, Kn, DH, S_LEN);
  transpose_cvt_k<<<NHEADS * (S_LEN / 64), 256, 0, stream>>>(v, Vt, S_LEN, DH);
  attn_k<<<NHEADS * (S_LEN / 128), 320, 0, stream>>>(Qb, Kn, Vt, Og, Pg);
}

// Round 14
// 350.212 us; speedup vs baseline: 1.3329x; 1.3329x over previous
//
#include <hip/hip_runtime.h>

// Scaled-dot-product attention, bs=4, h=16, S=2048, D=64, f32 in/out.
// Outputs O [64,2048,64] and P=attn_weights [64,2048,2048] (f32, 1.07 GB write).
// Confirmed levers: full-128B-line stores (R7 +13%); nt full-line stores
// bypassing L2 write-allocate (R10 +25%). R13 (wave specialization): regression.
// R14 model: machine-wide PHASE LOCK -- grid == resident capacity, all blocks
// run pass1 (no stores, ~1/3 of time) then pass2 (all stores) in lockstep, so
// the HBM write pipe idles 1/3 of the kernel. Fix: 2-tile/wave software
// pipeline: main loop does pass2(A) + pass1(B) per j-tile, SHARING the K tile
// registers. Stores flow ~2/3 of wave lifetime; same total MFMA count.

#define S_LEN 2048
#define DH 64
#define NHEADS 64  // bs*h

typedef short short8 __attribute__((ext_vector_type(8)));   // 8 x bf16
typedef float f32x4 __attribute__((ext_vector_type(4)));
typedef float f32x16 __attribute__((ext_vector_type(16)));
typedef unsigned short u16;

__device__ __forceinline__ u16 f2bf(float f) {
  union { float f; unsigned u; } x;
  x.f = f;
  unsigned r = x.u + 0x7fffu + ((x.u >> 16) & 1u);  // RNE
  return (u16)(r >> 16);
}

__device__ __forceinline__ unsigned pkbf(float a, float b) {
  return (unsigned)f2bf(a) | ((unsigned)f2bf(b) << 16);  // a -> low, b -> high
}

// v_permlane32_swap_b32: new a[32+i]=old b[i]; new b[i]=old a[32+i]
__device__ __forceinline__ void plswap(unsigned& a, unsigned& b) {
  asm("v_permlane32_swap_b32 %0, %1" : "+v"(a), "+v"(b));
}

// ---- pre-pass: Q * scale -> bf16, same layout ----
__global__ __launch_bounds__(256) void cvt_scale_k(const float* __restrict__ in,
                                                   u16* __restrict__ out,
                                                   float scale, int n4) {
  int i = blockIdx.x * 256 + threadIdx.x;
  if (i >= n4) return;
  float4 v = ((const float4*)in)[i];
  union { u16 s[4]; unsigned long long ll; } o;
  o.s[0] = f2bf(v.x * scale); o.s[1] = f2bf(v.y * scale);
  o.s[2] = f2bf(v.z * scale); o.s[3] = f2bf(v.w * scale);
  ((unsigned long long*)out)[i] = o.ll;
}

// ---- pre-pass: per-head transpose [R][C] f32 -> [C][R] bf16 ----
__global__ __launch_bounds__(256) void transpose_cvt_k(const float* __restrict__ in,
                                                       u16* __restrict__ out,
                                                       int R, int C) {
  __shared__ float tile[64][65];
  const int tilesC = C >> 6;
  const int tilesPerHead = (R >> 6) * tilesC;
  int hb = blockIdx.x;
  int head = hb / tilesPerHead;
  int t = hb - head * tilesPerHead;
  int tr = t / tilesC, tc = t - tr * tilesC;
  const float* ip = in + (size_t)head * R * C + (size_t)tr * 64 * C + (size_t)tc * 64;
  u16* op = out + (size_t)head * R * C + (size_t)tc * 64 * R + (size_t)tr * 64;
  int c = threadIdx.x & 63, r0 = threadIdx.x >> 6;
#pragma unroll
  for (int k = 0; k < 16; ++k) {
    int r = (k << 2) + r0;
    tile[r][c] = ip[(size_t)r * C + c];
  }
  __syncthreads();
#pragma unroll
  for (int k = 0; k < 16; ++k) {
    int orow = (k << 2) + r0;
    op[(size_t)orow * R + c] = f2bf(tile[c][orow]);
  }
}

// ---- fused attention, 2-tile/wave pipeline, nt full-line stores ----
// Layouts (bf16): Qb [h][s][d] (pre-scaled), Kn [h][s][d], Vt [h][d][s].
// Block = 4 waves; wave owns tiles A (q0) and B (q0+128), 32 rows each.
// mfma_f32_32x32x16_bf16:  A row=lane&31, k=(lane>>5)*8+i (8 contig)
//                          B col=lane&31, k=(lane>>5)*8+i
//                          D col=lane&31, row=(r&3)+8*(r>>2)+4*(lane>>5)
__global__ __launch_bounds__(256, 2) void attn_k(const u16* __restrict__ Qb,
                                                 const u16* __restrict__ Kn,
                                                 const u16* __restrict__ Vt,
                                                 float* __restrict__ Og,
                                                 float* __restrict__ Pg) {
  // per-wave 32x32 f32 transpose tile; row stride 32 floats (128 B).
  __shared__ float tile[4][32 * 32];
  int bid = blockIdx.x;
  // bijective XCD swizzle: 512 blocks, XCD x gets heads 8x..8x+7
  int work = ((bid & 7) << 6) | (bid >> 3);
  int head = work >> 3;
  int rblk = work & 7;                  // 8 row-blocks of 256 q-rows
  int lane = threadIdx.x & 63;
  int wv = threadIdx.x >> 6;
  int q = lane & 31;
  int hi = lane >> 5;
  int q0A = (rblk << 8) + (wv << 5);    // tile A rows
  int q0B = q0A + 128;                  // tile B rows
  float* tw = tile[wv];
  int rq = lane >> 3;   // 0..7: row-within-group for line stores
  int rc = lane & 7;    // 0..7: 16B chunk within the 128B line

  // Q fragments for both tiles, resident
  const u16* qpA = Qb + (size_t)(head * S_LEN + q0A + q) * DH + hi * 8;
  short8 qa0 = *(const short8*)(qpA);
  short8 qa1 = *(const short8*)(qpA + 16);
  short8 qa2 = *(const short8*)(qpA + 32);
  short8 qa3 = *(const short8*)(qpA + 48);
  const u16* qpB = Qb + (size_t)(head * S_LEN + q0B + q) * DH + hi * 8;
  short8 qb0 = *(const short8*)(qpB);
  short8 qb1 = *(const short8*)(qpB + 16);
  short8 qb2 = *(const short8*)(qpB + 32);
  short8 qb3 = *(const short8*)(qpB + 48);

  const u16* kp = Kn + (size_t)head * S_LEN * DH + (size_t)q * DH + hi * 8;
  const u16* vp = Vt + (size_t)head * DH * S_LEN + (size_t)q * S_LEN + hi * 8;

  // ---- phase 1: lA = sum_j exp(sA) ----
  float la0 = 0.f, la1 = 0.f, la2 = 0.f, la3 = 0.f;
  for (int j0 = 0; j0 < S_LEN; j0 += 32) {
    const u16* kb = kp + (size_t)j0 * DH;
    short8 k0 = *(const short8*)(kb);
    short8 k1 = *(const short8*)(kb + 16);
    short8 k2 = *(const short8*)(kb + 32);
    short8 k3 = *(const short8*)(kb + 48);
    f32x16 s = {};
    s = __builtin_amdgcn_mfma_f32_32x32x16_bf16(k0, qa0, s, 0, 0, 0);
    s = __builtin_amdgcn_mfma_f32_32x32x16_bf16(k1, qa1, s, 0, 0, 0);
    s = __builtin_amdgcn_mfma_f32_32x32x16_bf16(k2, qa2, s, 0, 0, 0);
    s = __builtin_amdgcn_mfma_f32_32x32x16_bf16(k3, qa3, s, 0, 0, 0);
#pragma unroll
    for (int r = 0; r < 16; r += 4) {
      la0 += __expf(s[r]);
      la1 += __expf(s[r + 1]);
      la2 += __expf(s[r + 2]);
      la3 += __expf(s[r + 3]);
    }
  }
  float lsA = (la0 + la1) + (la2 + la3);
  lsA += __shfl_xor(lsA, 32);
  float rlA = 1.f / lsA;

  // ---- phase 2: pass2(A) + pass1(B), sharing K tiles ----
  f32x16 oa = {}, ob = {};
  float lb0 = 0.f, lb1 = 0.f, lb2 = 0.f, lb3 = 0.f;
  float* pbA = Pg + (size_t)(head * S_LEN + q0A) * S_LEN;

  for (int j0 = 0; j0 < S_LEN; j0 += 32) {
    const u16* kb = kp + (size_t)j0 * DH;
    short8 k0 = *(const short8*)(kb);
    short8 k1 = *(const short8*)(kb + 16);
    short8 k2 = *(const short8*)(kb + 32);
    short8 k3 = *(const short8*)(kb + 48);
    const u16* vj = vp + j0;
    short8 v0 = *(const short8*)(vj);
    short8 v1 = *(const short8*)(vj + 16);
    short8 v2 = *(const short8*)(vj + 32 * S_LEN);
    short8 v3 = *(const short8*)(vj + 32 * S_LEN + 16);

    f32x16 s = {};
    s = __builtin_amdgcn_mfma_f32_32x32x16_bf16(k0, qa0, s, 0, 0, 0);
    s = __builtin_amdgcn_mfma_f32_32x32x16_bf16(k1, qa1, s, 0, 0, 0);
    s = __builtin_amdgcn_mfma_f32_32x32x16_bf16(k2, qa2, s, 0, 0, 0);
    s = __builtin_amdgcn_mfma_f32_32x32x16_bf16(k3, qa3, s, 0, 0, 0);

    float p[16];
#pragma unroll
    for (int r = 0; r < 16; ++r) p[r] = __expf(s[r]) * rlA;

    // LDS transpose write (chunk-XOR swizzle, ~4-way)
#pragma unroll
    for (int g = 0; g < 4; ++g) {
      int phys = (2 * g + hi) ^ (q & 7);
      f32x4 w = {p[4 * g], p[4 * g + 1], p[4 * g + 2], p[4 * g + 3]};
      *(f32x4*)&tw[q * 32 + phys * 4] = w;
    }

    // T12 redistribute: D-layout -> A-frag
    unsigned A0 = pkbf(p[0], p[1]),   A1 = pkbf(p[2], p[3]);
    unsigned B0 = pkbf(p[4], p[5]),   B1 = pkbf(p[6], p[7]);
    plswap(A0, B0);
    plswap(A1, B1);
    unsigned C0 = pkbf(p[8], p[9]),   C1 = pkbf(p[10], p[11]);
    unsigned D0 = pkbf(p[12], p[13]), D1 = pkbf(p[14], p[15]);
    plswap(C0, D0);
    plswap(C1, D1);
    union { unsigned w[4]; short8 v; } pa0u = {{A0, A1, B0, B1}};
    union { unsigned w[4]; short8 v; } pa1u = {{C0, C1, D0, D1}};

    oa = __builtin_amdgcn_mfma_f32_32x32x16_bf16(pa0u.v, v0, oa, 0, 0, 0);
    oa = __builtin_amdgcn_mfma_f32_32x32x16_bf16(pa1u.v, v1, oa, 0, 0, 0);
    ob = __builtin_amdgcn_mfma_f32_32x32x16_bf16(pa0u.v, v2, ob, 0, 0, 0);
    ob = __builtin_amdgcn_mfma_f32_32x32x16_bf16(pa1u.v, v3, ob, 0, 0, 0);

    // full-line nt P_A stores
    float* ps = pbA + j0;
#pragma unroll
    for (int g = 0; g < 4; ++g) {
      int qi = 8 * g + rq;
      int phys = rc ^ (qi & 7);
      f32x4 v = *(const f32x4*)&tw[qi * 32 + phys * 4];
      __builtin_nontemporal_store(v, (f32x4*)(ps + (size_t)qi * S_LEN + rc * 4));
    }

    // pass1(B) on the SAME K registers
    f32x16 sb = {};
    sb = __builtin_amdgcn_mfma_f32_32x32x16_bf16(k0, qb0, sb, 0, 0, 0);
    sb = __builtin_amdgcn_mfma_f32_32x32x16_bf16(k1, qb1, sb, 0, 0, 0);
    sb = __builtin_amdgcn_mfma_f32_32x32x16_bf16(k2, qb2, sb, 0, 0, 0);
    sb = __builtin_amdgcn_mfma_f32_32x32x16_bf16(k3, qb3, sb, 0, 0, 0);
#pragma unroll
    for (int r = 0; r < 16; r += 4) {
      lb0 += __expf(sb[r]);
      lb1 += __expf(sb[r + 1]);
      lb2 += __expf(sb[r + 2]);
      lb3 += __expf(sb[r + 3]);
    }
  }

  // ---- O_A epilogue (frees oa/ob for tile B) ----
  float* ogA = Og + (size_t)(head * S_LEN + q0A) * DH;
#pragma unroll
  for (int r = 0; r < 16; ++r) {
    int qi = (r & 3) + 8 * (r >> 2) + 4 * hi;
    tw[qi * 32 + q] = oa[r];
  }
#pragma unroll
  for (int g = 0; g < 4; ++g) {
    int qi = 8 * g + rq;
    f32x4 v = *(const f32x4*)&tw[qi * 32 + rc * 4];
    __builtin_nontemporal_store(v, (f32x4*)(ogA + (size_t)qi * DH + rc * 4));
  }
#pragma unroll
  for (int r = 0; r < 16; ++r) {
    int qi = (r & 3) + 8 * (r >> 2) + 4 * hi;
    tw[qi * 32 + q] = ob[r];
  }
#pragma unroll
  for (int g = 0; g < 4; ++g) {
    int qi = 8 * g + rq;
    f32x4 v = *(const f32x4*)&tw[qi * 32 + rc * 4];
    __builtin_nontemporal_store(v, (f32x4*)(ogA + (size_t)qi * DH + 32 + rc * 4));
  }

  float lsB = (lb0 + lb1) + (lb2 + lb3);
  lsB += __shfl_xor(lsB, 32);
  float rlB = 1.f / lsB;

  // ---- phase 3: pass2(B) ----
  oa = (f32x16){};
  ob = (f32x16){};
  float* pbB = Pg + (size_t)(head * S_LEN + q0B) * S_LEN;

  for (int j0 = 0; j0 < S_LEN; j0 += 32) {
    const u16* kb = kp + (size_t)j0 * DH;
    short8 k0 = *(const short8*)(kb);
    short8 k1 = *(const short8*)(kb + 16);
    short8 k2 = *(const short8*)(kb + 32);
    short8 k3 = *(const short8*)(kb + 48);
    const u16* vj = vp + j0;
    short8 v0 = *(const short8*)(vj);
    short8 v1 = *(const short8*)(vj + 16);
    short8 v2 = *(const short8*)(vj + 32 * S_LEN);
    short8 v3 = *(const short8*)(vj + 32 * S_LEN + 16);

    f32x16 s = {};
    s = __builtin_amdgcn_mfma_f32_32x32x16_bf16(k0, qb0, s, 0, 0, 0);
    s = __builtin_amdgcn_mfma_f32_32x32x16_bf16(k1, qb1, s, 0, 0, 0);
    s = __builtin_amdgcn_mfma_f32_32x32x16_bf16(k2, qb2, s, 0, 0, 0);
    s = __builtin_amdgcn_mfma_f32_32x32x16_bf16(k3, qb3, s, 0, 0, 0);

    float p[16];
#pragma unroll
    for (int r = 0; r < 16; ++r) p[r] = __expf(s[r]) * rlB;

#pragma unroll
    for (int g = 0; g < 4; ++g) {
      int phys = (2 * g + hi) ^ (q & 7);
      f32x4 w = {p[4 * g], p[4 * g + 1], p[4 * g + 2], p[4 * g + 3]};
      *(f32x4*)&tw[q * 32 + phys * 4] = w;
    }

    unsigned A0 = pkbf(p[0], p[1]),   A1 = pkbf(p[2], p[3]);
    unsigned B0 = pkbf(p[4], p[5]),   B1 = pkbf(p[6], p[7]);
    plswap(A0, B0);
    plswap(A1, B1);
    unsigned C0 = pkbf(p[8], p[9]),   C1 = pkbf(p[10], p[11]);
    unsigned D0 = pkbf(p[12], p[13]), D1 = pkbf(p[14], p[15]);
    plswap(C0, D0);
    plswap(C1, D1);
    union { unsigned w[4]; short8 v; } pa0u = {{A0, A1, B0, B1}};
    union { unsigned w[4]; short8 v; } pa1u = {{C0, C1, D0, D1}};

    oa = __builtin_amdgcn_mfma_f32_32x32x16_bf16(pa0u.v, v0, oa, 0, 0, 0);
    oa = __builtin_amdgcn_mfma_f32_32x32x16_bf16(pa1u.v, v1, oa, 0, 0, 0);
    ob = __builtin_amdgcn_mfma_f32_32x32x16_bf16(pa0u.v, v2, ob, 0, 0, 0);
    ob = __builtin_amdgcn_mfma_f32_32x32x16_bf16(pa1u.v, v3, ob, 0, 0, 0);

    float* ps = pbB + j0;
#pragma unroll
    for (int g = 0; g < 4; ++g) {
      int qi = 8 * g + rq;
      int phys = rc ^ (qi & 7);
      f32x4 v = *(const f32x4*)&tw[qi * 32 + phys * 4];
      __builtin_nontemporal_store(v, (f32x4*)(ps + (size_t)qi * S_LEN + rc * 4));
    }
  }

  // ---- O_B epilogue ----
  float* ogB = Og + (size_t)(head * S_LEN + q0B) * DH;
#pragma unroll
  for (int r = 0; r < 16; ++r) {
    int qi = (r & 3) + 8 * (r >> 2) + 4 * hi;
    tw[qi * 32 + q] = oa[r];
  }
#pragma unroll
  for (int g = 0; g < 4; ++g) {
    int qi = 8 * g + rq;
    f32x4 v = *(const f32x4*)&tw[qi * 32 + rc * 4];
    __builtin_nontemporal_store(v, (f32x4*)(ogB + (size_t)qi * DH + rc * 4));
  }
#pragma unroll
  for (int r = 0; r < 16; ++r) {
    int qi = (r & 3) + 8 * (r >> 2) + 4 * hi;
    tw[qi * 32 + q] = ob[r];
  }
#pragma unroll
  for (int g = 0; g < 4; ++g) {
    int qi = 8 * g + rq;
    f32x4 v = *(const f32x4*)&tw[qi * 32 + rc * 4];
    __builtin_nontemporal_store(v, (f32x4*)(ogB + (size_t)qi * DH + 32 + rc * 4));
  }
}

extern "C" void kernel_launch(void* const* d_in, const int* in_sizes, int n_in,
                              void* d_out, int out_size, void* d_ws, size_t ws_size,
                              hipStream_t stream) {
  const float* q = (const float*)d_in[0];
  const float* k = (const float*)d_in[1];  // [b,h,d,s]
  const float* v = (const float*)d_in[2];  // [b,h,s,d]
  float* Og = (float*)d_out;
  float* Pg = Og + (size_t)NHEADS * S_LEN * DH;

  const size_t elems = (size_t)NHEADS * S_LEN * DH;  // 8,388,608
  u16* Qb = (u16*)d_ws;           // bf16 [h][s][d], pre-scaled
  u16* Kn = Qb + elems;           // bf16 [h][s][d]
  u16* Vt = Kn + elems;           // bf16 [h][d][s]

  int n4 = (int)(elems / 4);
  cvt_scale_k<<<n4 / 256, 256, 0, stream>>>(q, Qb, 0.125f, n4);
  transpose_cvt_k<<<NHEADS * (S_LEN / 64), 256, 0, stream>>>(k, Kn, DH, S_LEN);
  transpose_cvt_k<<<NHEADS * (S_LEN / 64), 256, 0, stream>>>(v, Vt, S_LEN, DH);
  attn_k<<<NHEADS * (S_LEN / 256), 256, 0, stream>>>(Qb, Kn, Vt, Og, Pg);
}

// Round 15
// 350.099 us; speedup vs baseline: 1.3333x; 1.0003x over previous
//
#include <hip/hip_runtime.h>

// Scaled-dot-product attention, bs=4, h=16, S=2048, D=64, f32 in/out.
// Outputs O [64,2048,64] and P=attn_weights [64,2048,2048] (f32, 1.07 GB write).
// Confirmed levers: full-128B-line stores (R7 +13%); nt full-line stores
// bypassing L2 write-allocate (R10 +25%); 2-tile/wave pipeline widening the
// store duty cycle (R14 +13%).
// R15 model: vmcnt is shared loads+stores and retires IN ORDER (m135). R14's
// K/V loads are YOUNGER than the prior iter's nt stores, so the QK^T waitcnt
// drags the nt store ack (MC-side, slow) onto the critical path every iter.
// Fix: K/V prefetched ONE ITER AHEAD with issue order pinned by
// sched_barrier(0) (no wait introduced; compiler cannot sink the loads).
// Awaited loads are then always OLDER than outstanding stores -> retire
// independently. R5/R6 never tested this (VGPR=48 = loads were sunk).

#define S_LEN 2048
#define DH 64
#define NHEADS 64  // bs*h

typedef short short8 __attribute__((ext_vector_type(8)));   // 8 x bf16
typedef float f32x4 __attribute__((ext_vector_type(4)));
typedef float f32x16 __attribute__((ext_vector_type(16)));
typedef unsigned short u16;

__device__ __forceinline__ u16 f2bf(float f) {
  union { float f; unsigned u; } x;
  x.f = f;
  unsigned r = x.u + 0x7fffu + ((x.u >> 16) & 1u);  // RNE
  return (u16)(r >> 16);
}

__device__ __forceinline__ unsigned pkbf(float a, float b) {
  return (unsigned)f2bf(a) | ((unsigned)f2bf(b) << 16);  // a -> low, b -> high
}

// v_permlane32_swap_b32: new a[32+i]=old b[i]; new b[i]=old a[32+i]
__device__ __forceinline__ void plswap(unsigned& a, unsigned& b) {
  asm("v_permlane32_swap_b32 %0, %1" : "+v"(a), "+v"(b));
}

// ---- pre-pass: Q * scale -> bf16, same layout ----
__global__ __launch_bounds__(256) void cvt_scale_k(const float* __restrict__ in,
                                                   u16* __restrict__ out,
                                                   float scale, int n4) {
  int i = blockIdx.x * 256 + threadIdx.x;
  if (i >= n4) return;
  float4 v = ((const float4*)in)[i];
  union { u16 s[4]; unsigned long long ll; } o;
  o.s[0] = f2bf(v.x * scale); o.s[1] = f2bf(v.y * scale);
  o.s[2] = f2bf(v.z * scale); o.s[3] = f2bf(v.w * scale);
  ((unsigned long long*)out)[i] = o.ll;
}

// ---- pre-pass: per-head transpose [R][C] f32 -> [C][R] bf16 ----
__global__ __launch_bounds__(256) void transpose_cvt_k(const float* __restrict__ in,
                                                       u16* __restrict__ out,
                                                       int R, int C) {
  __shared__ float tile[64][65];
  const int tilesC = C >> 6;
  const int tilesPerHead = (R >> 6) * tilesC;
  int hb = blockIdx.x;
  int head = hb / tilesPerHead;
  int t = hb - head * tilesPerHead;
  int tr = t / tilesC, tc = t - tr * tilesC;
  const float* ip = in + (size_t)head * R * C + (size_t)tr * 64 * C + (size_t)tc * 64;
  u16* op = out + (size_t)head * R * C + (size_t)tc * 64 * R + (size_t)tr * 64;
  int c = threadIdx.x & 63, r0 = threadIdx.x >> 6;
#pragma unroll
  for (int k = 0; k < 16; ++k) {
    int r = (k << 2) + r0;
    tile[r][c] = ip[(size_t)r * C + c];
  }
  __syncthreads();
#pragma unroll
  for (int k = 0; k < 16; ++k) {
    int orow = (k << 2) + r0;
    op[(size_t)orow * R + c] = f2bf(tile[c][orow]);
  }
}

// ---- fused attention, 2-tile/wave pipeline + pinned K/V prefetch ----
// Layouts (bf16): Qb [h][s][d] (pre-scaled), Kn [h][s][d], Vt [h][d][s].
// Block = 4 waves; wave owns tiles A (q0) and B (q0+128), 32 rows each.
// mfma_f32_32x32x16_bf16:  A row=lane&31, k=(lane>>5)*8+i (8 contig)
//                          B col=lane&31, k=(lane>>5)*8+i
//                          D col=lane&31, row=(r&3)+8*(r>>2)+4*(lane>>5)
__global__ __launch_bounds__(256, 2) void attn_k(const u16* __restrict__ Qb,
                                                 const u16* __restrict__ Kn,
                                                 const u16* __restrict__ Vt,
                                                 float* __restrict__ Og,
                                                 float* __restrict__ Pg) {
  // per-wave 32x32 f32 transpose tile; row stride 32 floats (128 B).
  __shared__ float tile[4][32 * 32];
  int bid = blockIdx.x;
  // bijective XCD swizzle: 512 blocks, XCD x gets heads 8x..8x+7
  int work = ((bid & 7) << 6) | (bid >> 3);
  int head = work >> 3;
  int rblk = work & 7;                  // 8 row-blocks of 256 q-rows
  int lane = threadIdx.x & 63;
  int wv = threadIdx.x >> 6;
  int q = lane & 31;
  int hi = lane >> 5;
  int q0A = (rblk << 8) + (wv << 5);    // tile A rows
  int q0B = q0A + 128;                  // tile B rows
  float* tw = tile[wv];
  int rq = lane >> 3;   // 0..7: row-within-group for line stores
  int rc = lane & 7;    // 0..7: 16B chunk within the 128B line

  // Q fragments for both tiles, resident
  const u16* qpA = Qb + (size_t)(head * S_LEN + q0A + q) * DH + hi * 8;
  short8 qa0 = *(const short8*)(qpA);
  short8 qa1 = *(const short8*)(qpA + 16);
  short8 qa2 = *(const short8*)(qpA + 32);
  short8 qa3 = *(const short8*)(qpA + 48);
  const u16* qpB = Qb + (size_t)(head * S_LEN + q0B + q) * DH + hi * 8;
  short8 qb0 = *(const short8*)(qpB);
  short8 qb1 = *(const short8*)(qpB + 16);
  short8 qb2 = *(const short8*)(qpB + 32);
  short8 qb3 = *(const short8*)(qpB + 48);

  const u16* kp = Kn + (size_t)head * S_LEN * DH + (size_t)q * DH + hi * 8;
  const u16* vp = Vt + (size_t)head * DH * S_LEN + (size_t)q * S_LEN + hi * 8;

  // ---- phase 1: lA = sum_j exp(sA)  (no stores -> no chain; direct loads) ----
  float la0 = 0.f, la1 = 0.f, la2 = 0.f, la3 = 0.f;
  for (int j0 = 0; j0 < S_LEN; j0 += 32) {
    const u16* kb = kp + (size_t)j0 * DH;
    short8 k0 = *(const short8*)(kb);
    short8 k1 = *(const short8*)(kb + 16);
    short8 k2 = *(const short8*)(kb + 32);
    short8 k3 = *(const short8*)(kb + 48);
    f32x16 s = {};
    s = __builtin_amdgcn_mfma_f32_32x32x16_bf16(k0, qa0, s, 0, 0, 0);
    s = __builtin_amdgcn_mfma_f32_32x32x16_bf16(k1, qa1, s, 0, 0, 0);
    s = __builtin_amdgcn_mfma_f32_32x32x16_bf16(k2, qa2, s, 0, 0, 0);
    s = __builtin_amdgcn_mfma_f32_32x32x16_bf16(k3, qa3, s, 0, 0, 0);
#pragma unroll
    for (int r = 0; r < 16; r += 4) {
      la0 += __expf(s[r]);
      la1 += __expf(s[r + 1]);
      la2 += __expf(s[r + 2]);
      la3 += __expf(s[r + 3]);
    }
  }
  float lsA = (la0 + la1) + (la2 + la3);
  lsA += __shfl_xor(lsA, 32);
  float rlA = 1.f / lsA;

  // ---- phase 2: pass2(A) + pass1(B), K shared, K/V prefetched 1 iter ----
  f32x16 oa = {}, ob = {};
  float lb0 = 0.f, lb1 = 0.f, lb2 = 0.f, lb3 = 0.f;
  float* pbA = Pg + (size_t)(head * S_LEN + q0A) * S_LEN;

  short8 kc0 = *(const short8*)(kp);
  short8 kc1 = *(const short8*)(kp + 16);
  short8 kc2 = *(const short8*)(kp + 32);
  short8 kc3 = *(const short8*)(kp + 48);
  short8 vc0 = *(const short8*)(vp);
  short8 vc1 = *(const short8*)(vp + 16);
  short8 vc2 = *(const short8*)(vp + 32 * S_LEN);
  short8 vc3 = *(const short8*)(vp + 32 * S_LEN + 16);

  for (int j0 = 0; j0 < S_LEN; j0 += 32) {
    // prefetch next tile FIRST; sched_barrier pins issue before the stores
    // below, so next iter's waits are on loads OLDER than this iter's stores.
    int jn = (j0 + 32) & (S_LEN - 1);
    const u16* kb = kp + (size_t)jn * DH;
    short8 kn0 = *(const short8*)(kb);
    short8 kn1 = *(const short8*)(kb + 16);
    short8 kn2 = *(const short8*)(kb + 32);
    short8 kn3 = *(const short8*)(kb + 48);
    const u16* vj = vp + jn;
    short8 vn0 = *(const short8*)(vj);
    short8 vn1 = *(const short8*)(vj + 16);
    short8 vn2 = *(const short8*)(vj + 32 * S_LEN);
    short8 vn3 = *(const short8*)(vj + 32 * S_LEN + 16);
    __builtin_amdgcn_sched_barrier(0);

    f32x16 s = {};
    s = __builtin_amdgcn_mfma_f32_32x32x16_bf16(kc0, qa0, s, 0, 0, 0);
    s = __builtin_amdgcn_mfma_f32_32x32x16_bf16(kc1, qa1, s, 0, 0, 0);
    s = __builtin_amdgcn_mfma_f32_32x32x16_bf16(kc2, qa2, s, 0, 0, 0);
    s = __builtin_amdgcn_mfma_f32_32x32x16_bf16(kc3, qa3, s, 0, 0, 0);

    float p[16];
#pragma unroll
    for (int r = 0; r < 16; ++r) p[r] = __expf(s[r]) * rlA;

    // LDS transpose write (chunk-XOR swizzle, ~4-way)
#pragma unroll
    for (int g = 0; g < 4; ++g) {
      int phys = (2 * g + hi) ^ (q & 7);
      f32x4 w = {p[4 * g], p[4 * g + 1], p[4 * g + 2], p[4 * g + 3]};
      *(f32x4*)&tw[q * 32 + phys * 4] = w;
    }

    // T12 redistribute: D-layout -> A-frag
    unsigned A0 = pkbf(p[0], p[1]),   A1 = pkbf(p[2], p[3]);
    unsigned B0 = pkbf(p[4], p[5]),   B1 = pkbf(p[6], p[7]);
    plswap(A0, B0);
    plswap(A1, B1);
    unsigned C0 = pkbf(p[8], p[9]),   C1 = pkbf(p[10], p[11]);
    unsigned D0 = pkbf(p[12], p[13]), D1 = pkbf(p[14], p[15]);
    plswap(C0, D0);
    plswap(C1, D1);
    union { unsigned w[4]; short8 v; } pa0u = {{A0, A1, B0, B1}};
    union { unsigned w[4]; short8 v; } pa1u = {{C0, C1, D0, D1}};

    oa = __builtin_amdgcn_mfma_f32_32x32x16_bf16(pa0u.v, vc0, oa, 0, 0, 0);
    oa = __builtin_amdgcn_mfma_f32_32x32x16_bf16(pa1u.v, vc1, oa, 0, 0, 0);
    ob = __builtin_amdgcn_mfma_f32_32x32x16_bf16(pa0u.v, vc2, ob, 0, 0, 0);
    ob = __builtin_amdgcn_mfma_f32_32x32x16_bf16(pa1u.v, vc3, ob, 0, 0, 0);

    // pass1(B) on the SAME K registers
    f32x16 sb = {};
    sb = __builtin_amdgcn_mfma_f32_32x32x16_bf16(kc0, qb0, sb, 0, 0, 0);
    sb = __builtin_amdgcn_mfma_f32_32x32x16_bf16(kc1, qb1, sb, 0, 0, 0);
    sb = __builtin_amdgcn_mfma_f32_32x32x16_bf16(kc2, qb2, sb, 0, 0, 0);
    sb = __builtin_amdgcn_mfma_f32_32x32x16_bf16(kc3, qb3, sb, 0, 0, 0);
#pragma unroll
    for (int r = 0; r < 16; r += 4) {
      lb0 += __expf(sb[r]);
      lb1 += __expf(sb[r + 1]);
      lb2 += __expf(sb[r + 2]);
      lb3 += __expf(sb[r + 3]);
    }

    // full-line nt P_A stores -- LAST vmem of the body
    float* ps = pbA + j0;
#pragma unroll
    for (int g = 0; g < 4; ++g) {
      int qi = 8 * g + rq;
      int phys = rc ^ (qi & 7);
      f32x4 v = *(const f32x4*)&tw[qi * 32 + phys * 4];
      __builtin_nontemporal_store(v, (f32x4*)(ps + (size_t)qi * S_LEN + rc * 4));
    }

    kc0 = kn0; kc1 = kn1; kc2 = kn2; kc3 = kn3;
    vc0 = vn0; vc1 = vn1; vc2 = vn2; vc3 = vn3;
  }

  // ---- O_A epilogue ----
  float* ogA = Og + (size_t)(head * S_LEN + q0A) * DH;
#pragma unroll
  for (int r = 0; r < 16; ++r) {
    int qi = (r & 3) + 8 * (r >> 2) + 4 * hi;
    tw[qi * 32 + q] = oa[r];
  }
#pragma unroll
  for (int g = 0; g < 4; ++g) {
    int qi = 8 * g + rq;
    f32x4 v = *(const f32x4*)&tw[qi * 32 + rc * 4];
    __builtin_nontemporal_store(v, (f32x4*)(ogA + (size_t)qi * DH + rc * 4));
  }
#pragma unroll
  for (int r = 0; r < 16; ++r) {
    int qi = (r & 3) + 8 * (r >> 2) + 4 * hi;
    tw[qi * 32 + q] = ob[r];
  }
#pragma unroll
  for (int g = 0; g < 4; ++g) {
    int qi = 8 * g + rq;
    f32x4 v = *(const f32x4*)&tw[qi * 32 + rc * 4];
    __builtin_nontemporal_store(v, (f32x4*)(ogA + (size_t)qi * DH + 32 + rc * 4));
  }

  float lsB = (lb0 + lb1) + (lb2 + lb3);
  lsB += __shfl_xor(lsB, 32);
  float rlB = 1.f / lsB;

  // ---- phase 3: pass2(B), K/V prefetched 1 iter ----
  oa = (f32x16){};
  ob = (f32x16){};
  float* pbB = Pg + (size_t)(head * S_LEN + q0B) * S_LEN;

  kc0 = *(const short8*)(kp);
  kc1 = *(const short8*)(kp + 16);
  kc2 = *(const short8*)(kp + 32);
  kc3 = *(const short8*)(kp + 48);
  vc0 = *(const short8*)(vp);
  vc1 = *(const short8*)(vp + 16);
  vc2 = *(const short8*)(vp + 32 * S_LEN);
  vc3 = *(const short8*)(vp + 32 * S_LEN + 16);

  for (int j0 = 0; j0 < S_LEN; j0 += 32) {
    int jn = (j0 + 32) & (S_LEN - 1);
    const u16* kb = kp + (size_t)jn * DH;
    short8 kn0 = *(const short8*)(kb);
    short8 kn1 = *(const short8*)(kb + 16);
    short8 kn2 = *(const short8*)(kb + 32);
    short8 kn3 = *(const short8*)(kb + 48);
    const u16* vj = vp + jn;
    short8 vn0 = *(const short8*)(vj);
    short8 vn1 = *(const short8*)(vj + 16);
    short8 vn2 = *(const short8*)(vj + 32 * S_LEN);
    short8 vn3 = *(const short8*)(vj + 32 * S_LEN + 16);
    __builtin_amdgcn_sched_barrier(0);

    f32x16 s = {};
    s = __builtin_amdgcn_mfma_f32_32x32x16_bf16(kc0, qb0, s, 0, 0, 0);
    s = __builtin_amdgcn_mfma_f32_32x32x16_bf16(kc1, qb1, s, 0, 0, 0);
    s = __builtin_amdgcn_mfma_f32_32x32x16_bf16(kc2, qb2, s, 0, 0, 0);
    s = __builtin_amdgcn_mfma_f32_32x32x16_bf16(kc3, qb3, s, 0, 0, 0);

    float p[16];
#pragma unroll
    for (int r = 0; r < 16; ++r) p[r] = __expf(s[r]) * rlB;

#pragma unroll
    for (int g = 0; g < 4; ++g) {
      int phys = (2 * g + hi) ^ (q & 7);
      f32x4 w = {p[4 * g], p[4 * g + 1], p[4 * g + 2], p[4 * g + 3]};
      *(f32x4*)&tw[q * 32 + phys * 4] = w;
    }

    unsigned A0 = pkbf(p[0], p[1]),   A1 = pkbf(p[2], p[3]);
    unsigned B0 = pkbf(p[4], p[5]),   B1 = pkbf(p[6], p[7]);
    plswap(A0, B0);
    plswap(A1, B1);
    unsigned C0 = pkbf(p[8], p[9]),   C1 = pkbf(p[10], p[11]);
    unsigned D0 = pkbf(p[12], p[13]), D1 = pkbf(p[14], p[15]);
    plswap(C0, D0);
    plswap(C1, D1);
    union { unsigned w[4]; short8 v; } pa0u = {{A0, A1, B0, B1}};
    union { unsigned w[4]; short8 v; } pa1u = {{C0, C1, D0, D1}};

    oa = __builtin_amdgcn_mfma_f32_32x32x16_bf16(pa0u.v, vc0, oa, 0, 0, 0);
    oa = __builtin_amdgcn_mfma_f32_32x32x16_bf16(pa1u.v, vc1, oa, 0, 0, 0);
    ob = __builtin_amdgcn_mfma_f32_32x32x16_bf16(pa0u.v, vc2, ob, 0, 0, 0);
    ob = __builtin_amdgcn_mfma_f32_32x32x16_bf16(pa1u.v, vc3, ob, 0, 0, 0);

    float* ps = pbB + j0;
#pragma unroll
    for (int g = 0; g < 4; ++g) {
      int qi = 8 * g + rq;
      int phys = rc ^ (qi & 7);
      f32x4 v = *(const f32x4*)&tw[qi * 32 + phys * 4];
      __builtin_nontemporal_store(v, (f32x4*)(ps + (size_t)qi * S_LEN + rc * 4));
    }

    kc0 = kn0; kc1 = kn1; kc2 = kn2; kc3 = kn3;
    vc0 = vn0; vc1 = vn1; vc2 = vn2; vc3 = vn3;
  }

  // ---- O_B epilogue ----
  float* ogB = Og + (size_t)(head * S_LEN + q0B) * DH;
#pragma unroll
  for (int r = 0; r < 16; ++r) {
    int qi = (r & 3) + 8 * (r >> 2) + 4 * hi;
    tw[qi * 32 + q] = oa[r];
  }
#pragma unroll
  for (int g = 0; g < 4; ++g) {
    int qi = 8 * g + rq;
    f32x4 v = *(const f32x4*)&tw[qi * 32 + rc * 4];
    __builtin_nontemporal_store(v, (f32x4*)(ogB + (size_t)qi * DH + rc * 4));
  }
#pragma unroll
  for (int r = 0; r < 16; ++r) {
    int qi = (r & 3) + 8 * (r >> 2) + 4 * hi;
    tw[qi * 32 + q] = ob[r];
  }
#pragma unroll
  for (int g = 0; g < 4; ++g) {
    int qi = 8 * g + rq;
    f32x4 v = *(const f32x4*)&tw[qi * 32 + rc * 4];
    __builtin_nontemporal_store(v, (f32x4*)(ogB + (size_t)qi * DH + 32 + rc * 4));
  }
}

extern "C" void kernel_launch(void* const* d_in, const int* in_sizes, int n_in,
                              void* d_out, int out_size, void* d_ws, size_t ws_size,
                              hipStream_t stream) {
  const float* q = (const float*)d_in[0];
  const float* k = (const float*)d_in[1];  // [b,h,d,s]
  const float* v = (const float*)d_in[2];  // [b,h,s,d]
  float* Og = (float*)d_out;
  float* Pg = Og + (size_t)NHEADS * S_LEN * DH;

  const size_t elems = (size_t)NHEADS * S_LEN * DH;  // 8,388,608
  u16* Qb = (u16*)d_ws;           // bf16 [h][s][d], pre-scaled
  u16* Kn = Qb + elems;           // bf16 [h][s][d]
  u16* Vt = Kn + elems;           // bf16 [h][d][s]

  int n4 = (int)(elems / 4);
  cvt_scale_k<<<n4 / 256, 256, 0, stream>>>(q, Qb, 0.125f, n4);
  transpose_cvt_k<<<NHEADS * (S_LEN / 64), 256, 0, stream>>>(k, Kn, DH, S_LEN);
  transpose_cvt_k<<<NHEADS * (S_LEN / 64), 256, 0, stream>>>(v, Vt, S_LEN, DH);
  attn_k<<<NHEADS * (S_LEN / 256), 256, 0, stream>>>(Qb, Kn, Vt, Og, Pg);
}